// Round 13
// baseline (261.383 us; speedup 1.0000x reference)
//
#include <hip/hip_runtime.h>
#include <hip/hip_bf16.h>
#include <cstdint>

// Problem constants (from reference)
#define B_SZ   2
#define L_SEQ  2048
#define HID    4096
#define NH     16
#define NKV    4
#define HD     64
#define NQKV   (NH + 2*NKV)      // 24
#define QKV_N  (NQKV*HD)         // 1536
#define O_N    (NH*HD)           // 1024
#define M_ROWS (B_SZ*L_SEQ)      // 4096
#define EPSV   1e-6f

typedef __bf16  bf16x8_t  __attribute__((ext_vector_type(8)));
typedef float   f32x4_t   __attribute__((ext_vector_type(4)));
typedef unsigned short ushort8_t __attribute__((ext_vector_type(8)));

__device__ __forceinline__ unsigned short f2b(float f) {
    union { float f; uint32_t u; } v; v.f = f;
    uint32_t r = v.u + 0x7FFFu + ((v.u >> 16) & 1u);   // RNE to bf16
    return (unsigned short)(r >> 16);
}
__device__ __forceinline__ float b2f(unsigned short u) {
    union { uint32_t u; float f; } v; v.u = ((uint32_t)u) << 16;
    return v.f;
}

__device__ __forceinline__ void gload_lds16(const void* g, void* l) {
    __builtin_amdgcn_global_load_lds(
        (__attribute__((address_space(1))) void*)(g),
        (__attribute__((address_space(3))) void*)(l),
        16, 0, 0);
}

#define BARF() do { asm volatile("" ::: "memory"); \
                    __builtin_amdgcn_s_barrier();  \
                    asm volatile("" ::: "memory"); } while (0)
#define LGKMW() asm volatile("s_waitcnt lgkmcnt(0)" ::: "memory")

template <int N> __device__ __forceinline__ void vmcnt_wait() {
    if constexpr (N == 3)       asm volatile("s_waitcnt vmcnt(3)"  ::: "memory");
    else if constexpr (N == 4)  asm volatile("s_waitcnt vmcnt(4)"  ::: "memory");
    else if constexpr (N == 5)  asm volatile("s_waitcnt vmcnt(5)"  ::: "memory");
    else if constexpr (N == 6)  asm volatile("s_waitcnt vmcnt(6)"  ::: "memory");
    else if constexpr (N == 7)  asm volatile("s_waitcnt vmcnt(7)"  ::: "memory");
    else if constexpr (N == 8)  asm volatile("s_waitcnt vmcnt(8)"  ::: "memory");
    else if constexpr (N == 10) asm volatile("s_waitcnt vmcnt(10)" ::: "memory");
    else if constexpr (N == 12) asm volatile("s_waitcnt vmcnt(12)" ::: "memory");
    else                        asm volatile("s_waitcnt vmcnt(0)"  ::: "memory");
}

__device__ __forceinline__ bf16x8_t cvt8(float4 lo, float4 hi) {
    bf16x8_t r;
    r[0] = (__bf16)lo.x; r[1] = (__bf16)lo.y; r[2] = (__bf16)lo.z; r[3] = (__bf16)lo.w;
    r[4] = (__bf16)hi.x; r[5] = (__bf16)hi.y; r[6] = (__bf16)hi.z; r[7] = (__bf16)hi.w;
    return r;
}

// ---- merged weight transposes: fp32 (R x C) -> bf16 (C x R), both weights --
__global__ __launch_bounds__(256) void transpose_both(const float* __restrict__ Wqkv,
                                                      unsigned short* __restrict__ WqkvT,
                                                      const float* __restrict__ Wo,
                                                      unsigned short* __restrict__ WoT) {
    __shared__ float t[32][33];
    const float* in;
    unsigned short* out;
    int R, C, bx, by;
    if (blockIdx.x < 6144) {
        in = Wqkv; out = WqkvT; R = HID; C = QKV_N;
        bx = blockIdx.x % 48; by = blockIdx.x / 48;
    } else {
        int b = blockIdx.x - 6144;
        in = Wo; out = WoT; R = O_N; C = HID;
        bx = b % 128; by = b / 128;
    }
    const int c0 = bx * 32;
    const int r0 = by * 32;
    const int tx = threadIdx.x & 31;
    const int ty = threadIdx.x >> 5;
    #pragma unroll
    for (int i = 0; i < 32; i += 8)
        t[ty + i][tx] = in[(size_t)(r0 + ty + i) * C + c0 + tx];
    __syncthreads();
    #pragma unroll
    for (int i = 0; i < 32; i += 8)
        out[(size_t)(c0 + ty + i) * R + r0 + tx] = f2b(t[tx][ty + i]);
}

// ===========================================================================
// GEMM1 (fused fp32-A): qkvb = cvt_bf16(hid) @ WqkvT^T.  M=4096 N=1536 K=4096.
//   128x192 tile, BK=64, 8 waves 2Mx4N (wave 64x48), 256 blocks (1/CU).
//   A staged as RAW FP32 via global_load_lds (no reg round-trip -> no early
//   vmcnt stall like round-10's reg-staging); converted to bf16 per-fragment
//   in registers AFTER the ds_read (32 v_cvt per tile per wave, hidden under
//   931 MFMA cyc/SIMD). B staged bf16 as before.
//   LDS 136 KiB: A fp32 2 bufs x 32 KB | B bf16 3 bufs x 24 KB.
//   Single barrier + counted vmcnt per tile:
//     issue order per tile t: [A(t+1) 4 gloads][B(t+2) 3 gloads];
//     end-of-tile gate vmcnt(3) retires A(t+1) (and older B(t+1)) while
//     B(t+2) stays in flight. A-lead ~1 tile (~900cy) vs LLC-warm hid
//     (~400-500cy) -> no stall. Hazards: A(t+1)->buf[(t+1)&1] was read at
//     t-1, done by barrier(t); B(t+2)->buf[(t-1)%3] same argument.
//   A LDS swizzle: 16B chunk c of the 256B row stored at c^((row&7)<<1)
//     (even XOR keeps the 32B fragment pair contiguous); read pattern has
//     8 lanes per chunk-column on distinct rows = same pattern as the bf16
//     path that measures 0 bank conflicts.
// ===========================================================================
__global__ __launch_bounds__(512, 2)
void gemm1_af32(const float* __restrict__ A32,
                const unsigned short* __restrict__ Bt,
                unsigned short* __restrict__ C) {
    constexpr int AF = 4, BF = 3, Kd = HID, NT = HID / 64;   // 64 tiles

    __shared__ unsigned short smem[69632];   // 136 KiB

    const int tid  = threadIdx.x;
    const int lane = tid & 63;
    const int wave = tid >> 6;
    const int wm   = wave >> 2;            // 0..1 (M half, 64 rows)
    const int wn   = wave & 3;             // 0..3 (N quarter, 48 cols)
    const int fr   = lane & 15;
    const int fq   = lane >> 4;

    const int nbx = QKV_N / 192;           // 8
    int bid = blockIdx.x;
    const int cpx = gridDim.x >> 3;
    bid = (bid & 7) * cpx + (bid >> 3);
    const int bx = bid % nbx, by = bid / nbx;
    const int m0 = by * 128, n0 = bx * 192;

    float* As          = (float*)smem;     // 2 bufs x 8192 floats (32 KB)
    unsigned short* Bs = smem + 32768;     // 3 bufs x 12288 shorts (24 KB)

    // A staging: round q covers rows q*32 + (tid>>4); 16B f32-chunk tid&15
    const int srA = tid >> 4;
    const int scA = ((tid & 15) ^ ((srA & 7) << 1)) << 2;   // f32 offset in row
    const float* gA = A32 + (size_t)(m0 + srA) * Kd + scA;

    // B staging: round q covers rows q*64 + (tid>>3); 16B chunk tid&7
    const int srB = tid >> 3;
    const int scB = ((tid & 7) ^ (srB & 7)) << 3;
    const unsigned short* gB = Bt + (size_t)(n0 + srB) * Kd + scB;

    const int frsw = fr & 7;

    f32x4_t acc[AF][BF];
    #pragma unroll
    for (int m = 0; m < AF; m++)
        #pragma unroll
        for (int n = 0; n < BF; n++)
            acc[m][n] = (f32x4_t){0.f, 0.f, 0.f, 0.f};

    auto STAGE_A = [&](int T) {
        float* dst = As + (T & 1) * 8192;
        #pragma unroll
        for (int q = 0; q < 4; ++q)
            gload_lds16(gA + (size_t)(q * 32) * Kd + (size_t)T * 64,
                        dst + q * 2048 + tid * 4);
    };
    auto STAGE_B = [&](int T) {
        unsigned short* dst = Bs + (T % 3) * 12288;
        #pragma unroll
        for (int q = 0; q < 3; ++q)
            gload_lds16(gB + (size_t)(q * 64) * Kd + (size_t)T * 64,
                        dst + q * 4096 + tid * 8);
    };

    // prologue: A0,B0,A1,B1 (14 loads); retire A0,B0 -> allow A1+B1 = 7
    STAGE_A(0); STAGE_B(0); STAGE_A(1); STAGE_B(1);
    vmcnt_wait<7>();

    for (int t = 0; t < NT; ++t) {
        const float* Ab          = As + (t & 1) * 8192;
        const unsigned short* Bb = Bs + (t % 3) * 12288;
        BARF();   // the ONLY barrier per tile

        #pragma unroll
        for (int kk = 0; kk < 2; ++kk) {
            bf16x8_t aF[AF], bF[BF];
            #pragma unroll
            for (int mm = 0; mm < AF; ++mm) {
                const int ar = wm * 64 + mm * 16 + fr;
                const int ac = ((kk * 8 + fq * 2) ^ (frsw << 1)) << 2;
                float4 lo = *(const float4*)&Ab[ar * 64 + ac];
                float4 hi = *(const float4*)&Ab[ar * 64 + ac + 4];
                aF[mm] = cvt8(lo, hi);
            }
            #pragma unroll
            for (int nn = 0; nn < BF; ++nn) {
                const int cxk = ((kk * 4 + fq) ^ frsw) << 3;
                bF[nn] = *(const bf16x8_t*)&Bb[(wn * 48 + nn * 16 + fr) * 64 + cxk];
            }

            if (kk == 0) {
                if (t >= 1 && t + 1 < NT) STAGE_A(t + 1);   // t=0: A1 pre-staged
                if (t + 2 < NT)           STAGE_B(t + 2);
            }

            __builtin_amdgcn_s_setprio(1);
            #pragma unroll
            for (int mm = 0; mm < AF; ++mm)
                #pragma unroll
                for (int nn = 0; nn < BF; ++nn)
                    acc[mm][nn] = __builtin_amdgcn_mfma_f32_16x16x32_bf16(
                        aF[mm], bF[nn], acc[mm][nn], 0, 0, 0);
            __builtin_amdgcn_s_setprio(0);
        }

        // gate: A(t+1) + B(t+1) landed; B(t+2)'s 3 stay in flight
        if (t + 2 < NT)      { vmcnt_wait<3>(); }
        else if (t + 1 < NT) { vmcnt_wait<0>(); }
    }

    // epilogue: bf16 out. C/D layout col=lane&15, row=(lane>>4)*4+reg
    const int crow = m0 + wm * 64 + fq * 4;
    const int ccol = n0 + wn * 48 + fr;
    #pragma unroll
    for (int m = 0; m < AF; m++)
        #pragma unroll
        for (int n = 0; n < BF; n++)
            #pragma unroll
            for (int rr = 0; rr < 4; rr++)
                C[(size_t)(crow + m*16 + rr) * QKV_N + ccol + n*16] = f2b(acc[m][n][rr]);
}

// ===========================================================================
// GEMM2: m201-style 8-phase schedule (round-12, kept).
//   out[4096,4096] = attnb @ WoT^T, K=1024. 256x256 tile, BK=64, grid 256.
// ===========================================================================
#define G2_BUF 32768   // shorts per buffer (64 KiB)

__global__ __launch_bounds__(512, 2)
void gemm2_8p(const unsigned short* __restrict__ A,
              const unsigned short* __restrict__ Bt,
              float* __restrict__ C) {
    constexpr int K     = O_N;        // 1024
    constexpr int N     = HID;        // 4096
    constexpr int NT    = K / 64;     // 16
    constexpr int NITER = NT / 2;     // 8

    __shared__ unsigned short smem[2 * G2_BUF];   // 128 KiB

    const int tid  = threadIdx.x;
    const int lane = tid & 63;
    const int wave = tid >> 6;
    const int wm   = wave >> 2;       // 0..1  (128 rows)
    const int wn   = wave & 3;        // 0..3  (64 cols)
    const int fr   = lane & 15;
    const int fq   = lane >> 4;

    const int nbx = N >> 8;           // 16
    int bid = blockIdx.x;
    const int cpx = gridDim.x >> 3;
    bid = (bid & 7) * cpx + (bid >> 3);
    const int bx = bid % nbx, by = bid / nbx;
    const int m0 = by << 8, n0 = bx << 8;

    const int srow = tid >> 3;
    const int scs  = ((tid & 7) ^ (srow & 7)) << 3;
    const unsigned short* gA = A  + (size_t)(m0 + srow) * K + scs;
    const unsigned short* gB = Bt + (size_t)(n0 + srow) * K + scs;
    const int frsw = fr & 7;

    f32x4_t acc[8][4];
    #pragma unroll
    for (int m = 0; m < 8; m++)
        #pragma unroll
        for (int n = 0; n < 4; n++)
            acc[m][n] = (f32x4_t){0.f, 0.f, 0.f, 0.f};

#define SA(T, q) gload_lds16(gA + (size_t)((q)*64)*K + (size_t)(T)*64, \
                             &smem[((T)&1)*G2_BUF + (q)*4096 + tid*8])
#define SB(T, q) gload_lds16(gB + (size_t)((q)*64)*K + (size_t)(T)*64, \
                             &smem[((T)&1)*G2_BUF + 16384 + (q)*4096 + tid*8])
#define RDA(T, MH, KI) { _Pragma("unroll") for (int mm = 0; mm < 4; ++mm) { \
    const int ro = ((T)&1)*G2_BUF + (wm*128 + (MH)*64 + mm*16 + fr)*64; \
    aF[mm] = *(const bf16x8_t*)&smem[ro + ((((KI)*4 + fq) ^ frsw) << 3)]; } }
#define RDB(T, KI, dst) { _Pragma("unroll") for (int nn = 0; nn < 4; ++nn) { \
    const int ro = ((T)&1)*G2_BUF + 16384 + (wn*64 + nn*16 + fr)*64; \
    dst[nn] = *(const bf16x8_t*)&smem[ro + ((((KI)*4 + fq) ^ frsw) << 3)]; } }
#define MM16(MH, BS) { __builtin_amdgcn_s_setprio(1); \
    _Pragma("unroll") for (int mm = 0; mm < 4; ++mm) \
    _Pragma("unroll") for (int nn = 0; nn < 4; ++nn) \
        acc[(MH)*4 + mm][nn] = __builtin_amdgcn_mfma_f32_16x16x32_bf16( \
            aF[mm], BS[nn], acc[(MH)*4 + mm][nn], 0, 0, 0); \
    __builtin_amdgcn_s_setprio(0); }

    SA(0,0); SA(0,1); SA(0,2); SA(0,3);
    SB(0,0); SB(0,1); SB(0,2); SB(0,3);
    SA(1,0); SA(1,2); SB(1,0); SB(1,1);
    vmcnt_wait<4>();
    BARF();

    for (int i = 0; i < NITER; ++i) {
        const int t0 = 2*i, t1 = 2*i + 1;
        bf16x8_t aF[4], b0[4], b1[4];

        RDA(t0, 0, 0); RDB(t0, 0, b0);
        SA(t1, 1); SA(t1, 3);
        BARF(); LGKMW(); MM16(0, b0); BARF();

        RDA(t0, 0, 1); RDB(t0, 1, b1);
        SB(t1, 2); SB(t1, 3);
        BARF(); LGKMW(); MM16(0, b1); BARF();

        RDA(t0, 1, 0);
        if (t0 + 2 < NT) { SA(t0 + 2, 0); SA(t0 + 2, 2); }
        BARF(); LGKMW(); MM16(1, b0); BARF();

        RDA(t0, 1, 1);
        if (t0 + 2 < NT) { SB(t0 + 2, 0); SB(t0 + 2, 1); }
        BARF(); LGKMW(); MM16(1, b1);
        if (i + 1 < NITER) { vmcnt_wait<4>(); } else { vmcnt_wait<0>(); }
        BARF();

        RDA(t1, 0, 0); RDB(t1, 0, b0);
        if (t0 + 2 < NT) { SA(t0 + 2, 1); SA(t0 + 2, 3); }
        BARF(); LGKMW(); MM16(0, b0); BARF();

        RDA(t1, 0, 1); RDB(t1, 1, b1);
        if (t0 + 2 < NT) { SB(t0 + 2, 2); SB(t0 + 2, 3); }
        BARF(); LGKMW(); MM16(0, b1); BARF();

        RDA(t1, 1, 0);
        if (t1 + 2 < NT) { SA(t1 + 2, 0); SA(t1 + 2, 2); }
        BARF(); LGKMW(); MM16(1, b0); BARF();

        RDA(t1, 1, 1);
        if (t1 + 2 < NT) { SB(t1 + 2, 0); SB(t1 + 2, 1); }
        BARF(); LGKMW(); MM16(1, b1);
        if (i + 1 < NITER) { vmcnt_wait<4>(); }
        BARF();
    }
#undef SA
#undef SB
#undef RDA
#undef RDB
#undef MM16

    const int crow = m0 + wm * 128 + fq * 4;
    const int ccol = n0 + wn * 64 + fr;
    #pragma unroll
    for (int m = 0; m < 8; m++)
        #pragma unroll
        for (int n = 0; n < 4; n++)
            #pragma unroll
            for (int rr = 0; rr < 4; rr++)
                C[(size_t)(crow + m*16 + rr) * N + ccol + n*16] = acc[m][n][rr];
}

// --------- fused RMSNorm + RoPE + 16-token block-diagonal attention --------
__global__ __launch_bounds__(64) void attn_fused(const unsigned short* __restrict__ qkv,
                                                 const float* __restrict__ cosb,
                                                 const float* __restrict__ sinb,
                                                 const float* __restrict__ qw,
                                                 const float* __restrict__ kw,
                                                 unsigned short* __restrict__ out) {
    const int h    = blockIdx.x & (NH - 1);
    const int blk  = (blockIdx.x >> 4) & 127;
    const int b    = blockIdx.x >> 11;
    const int pos0 = blk * 16;
    const int kvh  = h >> 2;

    const int lane = threadIdx.x;
    const int r    = lane >> 2;
    const int qp   = lane & 3;
    const int d0   = qp * 16;

    __shared__ float qs[16][65];
    __shared__ float ks[16][65];
    __shared__ float vs[16][65];
    __shared__ float ps[16][17];

    const size_t rowb = ((size_t)(b * L_SEQ + pos0 + r)) * NQKV;
    const unsigned short* qptr = qkv + (rowb + h) * HD + d0;
    const unsigned short* kptr = qkv + (rowb + NH + kvh) * HD + d0;
    const unsigned short* vptr = qkv + (rowb + NH + NKV + kvh) * HD + d0;
    const size_t csrow = ((size_t)(b * L_SEQ + pos0 + r)) * HD + d0;

    float q[16], k[16], v[16], cs[16], sn[16];
    {
        ushort8_t q0 = *(const ushort8_t*)&qptr[0], q1 = *(const ushort8_t*)&qptr[8];
        ushort8_t k0 = *(const ushort8_t*)&kptr[0], k1 = *(const ushort8_t*)&kptr[8];
        ushort8_t v0 = *(const ushort8_t*)&vptr[0], v1 = *(const ushort8_t*)&vptr[8];
        #pragma unroll
        for (int i = 0; i < 8; i++) {
            q[i] = b2f(q0[i]); q[i+8] = b2f(q1[i]);
            k[i] = b2f(k0[i]); k[i+8] = b2f(k1[i]);
            v[i] = b2f(v0[i]); v[i+8] = b2f(v1[i]);
        }
        #pragma unroll
        for (int i = 0; i < 16; i += 4) {
            *(float4*)&cs[i] = *(const float4*)&cosb[csrow + i];
            *(float4*)&sn[i] = *(const float4*)&sinb[csrow + i];
        }
    }

    float sq = 0.f, sk = 0.f;
    #pragma unroll
    for (int i = 0; i < 16; i++) { sq += q[i]*q[i]; sk += k[i]*k[i]; }
    sq += __shfl_xor(sq, 1); sq += __shfl_xor(sq, 2);
    sk += __shfl_xor(sk, 1); sk += __shfl_xor(sk, 2);
    const float rq = rsqrtf(sq * (1.f / HD) + EPSV);
    const float rk = rsqrtf(sk * (1.f / HD) + EPSV);

    const float sgn = (qp < 2) ? -1.f : 1.f;
    #pragma unroll
    for (int i = 0; i < 16; i++) {
        float qn = q[i] * rq * qw[d0 + i];
        float kn = k[i] * rk * kw[d0 + i];
        float qo = __shfl_xor(qn, 2);
        float ko = __shfl_xor(kn, 2);
        qs[r][d0 + i] = qn * cs[i] + sgn * qo * sn[i];
        ks[r][d0 + i] = kn * cs[i] + sgn * ko * sn[i];
        vs[r][d0 + i] = v[i];
    }
    __syncthreads();

    float sc[4] = {0.f, 0.f, 0.f, 0.f};
    for (int d = 0; d < 64; d++) {
        const float qd = qs[r][d];
        sc[0] += qd * ks[qp     ][d];
        sc[1] += qd * ks[qp +  4][d];
        sc[2] += qd * ks[qp +  8][d];
        sc[3] += qd * ks[qp + 12][d];
    }
    #pragma unroll
    for (int cc = 0; cc < 4; cc++) {
        const int c = qp + cc * 4;
        sc[cc] = (c <= r) ? sc[cc] * 0.125f : -3.0e38f;
    }
    float mx = fmaxf(fmaxf(sc[0], sc[1]), fmaxf(sc[2], sc[3]));
    mx = fmaxf(mx, __shfl_xor(mx, 1));
    mx = fmaxf(mx, __shfl_xor(mx, 2));
    float e[4], sum = 0.f;
    #pragma unroll
    for (int cc = 0; cc < 4; cc++) { e[cc] = __expf(sc[cc] - mx); sum += e[cc]; }
    sum += __shfl_xor(sum, 1); sum += __shfl_xor(sum, 2);
    const float inv = 1.f / sum;
    #pragma unroll
    for (int cc = 0; cc < 4; cc++) ps[r][qp + cc * 4] = e[cc] * inv;
    __syncthreads();

    float o[16];
    #pragma unroll
    for (int i = 0; i < 16; i++) o[i] = 0.f;
    #pragma unroll
    for (int c = 0; c < 16; c++) {
        const float p = ps[r][c];
        #pragma unroll
        for (int i = 0; i < 16; i++) o[i] += p * vs[c][d0 + i];
    }

    __attribute__((aligned(16))) unsigned short ob[16];
    #pragma unroll
    for (int i = 0; i < 16; i++) ob[i] = f2b(o[i]);
    unsigned short* optr = out + (((size_t)(b * L_SEQ + pos0 + r) * NH + h) * HD) + d0;
    *(uint4*)optr       = *(uint4*)&ob[0];
    *((uint4*)optr + 1) = *(uint4*)&ob[8];
}

// ---------------------------------------------------------------------------
extern "C" void kernel_launch(void* const* d_in, const int* in_sizes, int n_in,
                              void* d_out, int out_size, void* d_ws, size_t ws_size,
                              hipStream_t stream) {
    const float* hid  = (const float*)d_in[0];
    const float* cosb = (const float*)d_in[2];
    const float* sinb = (const float*)d_in[3];
    const float* Wqkv = (const float*)d_in[4];
    const float* Wo   = (const float*)d_in[5];
    const float* qw   = (const float*)d_in[6];
    const float* kw   = (const float*)d_in[7];
    float* outp = (float*)d_out;

    char* ws = (char*)d_ws;
    unsigned short* WqkvT = (unsigned short*)ws; ws += (size_t)QKV_N * HID * 2;
    unsigned short* WoT   = (unsigned short*)ws; ws += (size_t)HID * O_N * 2;
    unsigned short* qkvb  = (unsigned short*)ws; ws += (size_t)M_ROWS * QKV_N * 2;
    unsigned short* attnb = (unsigned short*)ws;

    // merged weight transposes
    transpose_both<<<dim3(6144 + 4096), 256, 0, stream>>>(Wqkv, WqkvT, Wo, WoT);

    // GEMM1 with fused fp32->bf16 A conversion via raw-fp32 global_load_lds
    // (cvt kernel ELIMINATED; no reg-staging stall this time)
    gemm1_af32<<<dim3((M_ROWS / 128) * (QKV_N / 192)), 512, 0, stream>>>
        (hid, WqkvT, qkvb);

    // fused rmsnorm + rope + block-diag attention (bf16 in/out)
    attn_fused<<<dim3(B_SZ * (L_SEQ / 16) * NH), 64, 0, stream>>>(qkvb, cosb, sinb, qw, kw, attnb);

    // GEMM2 (8-phase, kept from round 12)
    gemm2_8p<<<dim3((M_ROWS / 256) * (HID / 256)), 512, 0, stream>>>
        (attnb, WoT, outp);
}

// Round 14
// 156.632 us; speedup vs baseline: 1.6688x; 1.6688x over previous
//
#include <hip/hip_runtime.h>
#include <hip/hip_bf16.h>
#include <cstdint>

// Problem constants (from reference)
#define B_SZ   2
#define L_SEQ  2048
#define HID    4096
#define NH     16
#define NKV    4
#define HD     64
#define NQKV   (NH + 2*NKV)      // 24
#define QKV_N  (NQKV*HD)         // 1536
#define O_N    (NH*HD)           // 1024
#define M_ROWS (B_SZ*L_SEQ)      // 4096
#define EPSV   1e-6f

typedef __bf16  bf16x8_t  __attribute__((ext_vector_type(8)));
typedef float   f32x4_t   __attribute__((ext_vector_type(4)));
typedef unsigned short ushort8_t __attribute__((ext_vector_type(8)));

__device__ __forceinline__ unsigned short f2b(float f) {
    union { float f; uint32_t u; } v; v.f = f;
    uint32_t r = v.u + 0x7FFFu + ((v.u >> 16) & 1u);   // RNE to bf16
    return (unsigned short)(r >> 16);
}
__device__ __forceinline__ float b2f(unsigned short u) {
    union { uint32_t u; float f; } v; v.u = ((uint32_t)u) << 16;
    return v.f;
}

__device__ __forceinline__ void gload_lds16(const void* g, void* l) {
    __builtin_amdgcn_global_load_lds(
        (__attribute__((address_space(1))) void*)(g),
        (__attribute__((address_space(3))) void*)(l),
        16, 0, 0);
}

#define BARF() do { asm volatile("" ::: "memory"); \
                    __builtin_amdgcn_s_barrier();  \
                    asm volatile("" ::: "memory"); } while (0)
#define LGKMW() asm volatile("s_waitcnt lgkmcnt(0)" ::: "memory")

template <int N> __device__ __forceinline__ void vmcnt_wait() {
    if constexpr (N == 3)       asm volatile("s_waitcnt vmcnt(3)"  ::: "memory");
    else if constexpr (N == 4)  asm volatile("s_waitcnt vmcnt(4)"  ::: "memory");
    else if constexpr (N == 5)  asm volatile("s_waitcnt vmcnt(5)"  ::: "memory");
    else if constexpr (N == 6)  asm volatile("s_waitcnt vmcnt(6)"  ::: "memory");
    else if constexpr (N == 7)  asm volatile("s_waitcnt vmcnt(7)"  ::: "memory");
    else if constexpr (N == 8)  asm volatile("s_waitcnt vmcnt(8)"  ::: "memory");
    else if constexpr (N == 10) asm volatile("s_waitcnt vmcnt(10)" ::: "memory");
    else if constexpr (N == 12) asm volatile("s_waitcnt vmcnt(12)" ::: "memory");
    else                        asm volatile("s_waitcnt vmcnt(0)"  ::: "memory");
}

__device__ __forceinline__ bf16x8_t cvt8(float4 lo, float4 hi) {
    bf16x8_t r;
    r[0] = (__bf16)lo.x; r[1] = (__bf16)lo.y; r[2] = (__bf16)lo.z; r[3] = (__bf16)lo.w;
    r[4] = (__bf16)hi.x; r[5] = (__bf16)hi.y; r[6] = (__bf16)hi.z; r[7] = (__bf16)hi.w;
    return r;
}

// ---- merged weight transposes: fp32 (R x C) -> bf16 (C x R), both weights --
__global__ __launch_bounds__(256) void transpose_both(const float* __restrict__ Wqkv,
                                                      unsigned short* __restrict__ WqkvT,
                                                      const float* __restrict__ Wo,
                                                      unsigned short* __restrict__ WoT) {
    __shared__ float t[32][33];
    const float* in;
    unsigned short* out;
    int R, C, bx, by;
    if (blockIdx.x < 6144) {
        in = Wqkv; out = WqkvT; R = HID; C = QKV_N;
        bx = blockIdx.x % 48; by = blockIdx.x / 48;
    } else {
        int b = blockIdx.x - 6144;
        in = Wo; out = WoT; R = O_N; C = HID;
        bx = b % 128; by = b / 128;
    }
    const int c0 = bx * 32;
    const int r0 = by * 32;
    const int tx = threadIdx.x & 31;
    const int ty = threadIdx.x >> 5;
    #pragma unroll
    for (int i = 0; i < 32; i += 8)
        t[ty + i][tx] = in[(size_t)(r0 + ty + i) * C + c0 + tx];
    __syncthreads();
    #pragma unroll
    for (int i = 0; i < 32; i += 8)
        out[(size_t)(c0 + ty + i) * R + r0 + tx] = f2b(t[tx][ty + i]);
}

// ===========================================================================
// GEMM1 (fused fp32-A): qkvb = cvt_bf16(hid) @ WqkvT^T.  M=4096 N=1536 K=4096.
//   Structure identical to round 13 EXCEPT the A LDS swizzle.
//   FIXED A swizzle (round-13 postmortem: old 2x-granular XOR collapsed 16
//   fr-lanes onto 4 bank-slots -> 4-way conflict, 8.2e7 counted):
//     store chunk c of row r at c ^ (r&15); read logical chunk x of row ar
//     at x ^ (ar&15). ar&15 == fr, so (x^fr) mod 8 is uniform over the wave
//     -> exactly 2 lanes/bank (free). Involution verified: both sides use
//     the same 16B-granular XOR key (r&15).
// ===========================================================================
__global__ __launch_bounds__(512, 2)
void gemm1_af32(const float* __restrict__ A32,
                const unsigned short* __restrict__ Bt,
                unsigned short* __restrict__ C) {
    constexpr int AF = 4, BF = 3, Kd = HID, NT = HID / 64;   // 64 tiles

    __shared__ unsigned short smem[69632];   // 136 KiB

    const int tid  = threadIdx.x;
    const int lane = tid & 63;
    const int wave = tid >> 6;
    const int wm   = wave >> 2;            // 0..1 (M half, 64 rows)
    const int wn   = wave & 3;             // 0..3 (N quarter, 48 cols)
    const int fr   = lane & 15;
    const int fq   = lane >> 4;

    const int nbx = QKV_N / 192;           // 8
    int bid = blockIdx.x;
    const int cpx = gridDim.x >> 3;
    bid = (bid & 7) * cpx + (bid >> 3);
    const int bx = bid % nbx, by = bid / nbx;
    const int m0 = by * 128, n0 = bx * 192;

    float* As          = (float*)smem;     // 2 bufs x 8192 floats (32 KB)
    unsigned short* Bs = smem + 32768;     // 3 bufs x 12288 shorts (24 KB)

    // A staging: round q covers rows q*32 + (tid>>4); 16B chunk tid&15.
    // Pre-swizzled source: chunk (tid&15) ^ (row&15); row&15 == srA&15.
    const int srA = tid >> 4;
    const int scA = ((tid & 15) ^ (srA & 15)) << 2;   // f32 offset in row
    const float* gA = A32 + (size_t)(m0 + srA) * Kd + scA;

    // B staging: round q covers rows q*64 + (tid>>3); 16B chunk tid&7
    const int srB = tid >> 3;
    const int scB = ((tid & 7) ^ (srB & 7)) << 3;
    const unsigned short* gB = Bt + (size_t)(n0 + srB) * Kd + scB;

    const int frsw = fr & 7;

    f32x4_t acc[AF][BF];
    #pragma unroll
    for (int m = 0; m < AF; m++)
        #pragma unroll
        for (int n = 0; n < BF; n++)
            acc[m][n] = (f32x4_t){0.f, 0.f, 0.f, 0.f};

    auto STAGE_A = [&](int T) {
        float* dst = As + (T & 1) * 8192;
        #pragma unroll
        for (int q = 0; q < 4; ++q)
            gload_lds16(gA + (size_t)(q * 32) * Kd + (size_t)T * 64,
                        dst + q * 2048 + tid * 4);
    };
    auto STAGE_B = [&](int T) {
        unsigned short* dst = Bs + (T % 3) * 12288;
        #pragma unroll
        for (int q = 0; q < 3; ++q)
            gload_lds16(gB + (size_t)(q * 64) * Kd + (size_t)T * 64,
                        dst + q * 4096 + tid * 8);
    };

    // prologue: A0,B0,A1,B1 (14 loads); retire A0,B0 -> allow A1+B1 = 7
    STAGE_A(0); STAGE_B(0); STAGE_A(1); STAGE_B(1);
    vmcnt_wait<7>();

    for (int t = 0; t < NT; ++t) {
        const float* Ab          = As + (t & 1) * 8192;
        const unsigned short* Bb = Bs + (t % 3) * 12288;
        BARF();   // the ONLY barrier per tile

        #pragma unroll
        for (int kk = 0; kk < 2; ++kk) {
            bf16x8_t aF[AF], bF[BF];
            #pragma unroll
            for (int mm = 0; mm < AF; ++mm) {
                const int ar = wm * 64 + mm * 16 + fr;   // ar&15 == fr
                const int x0 = kk * 8 + fq * 2;          // logical 16B chunk
                float4 lo = *(const float4*)&Ab[ar * 64 + (((x0    ) ^ fr) << 2)];
                float4 hi = *(const float4*)&Ab[ar * 64 + (((x0 + 1) ^ fr) << 2)];
                aF[mm] = cvt8(lo, hi);
            }
            #pragma unroll
            for (int nn = 0; nn < BF; ++nn) {
                const int cxk = ((kk * 4 + fq) ^ frsw) << 3;
                bF[nn] = *(const bf16x8_t*)&Bb[(wn * 48 + nn * 16 + fr) * 64 + cxk];
            }

            if (kk == 0) {
                if (t >= 1 && t + 1 < NT) STAGE_A(t + 1);   // t=0: A1 pre-staged
                if (t + 2 < NT)           STAGE_B(t + 2);
            }

            __builtin_amdgcn_s_setprio(1);
            #pragma unroll
            for (int mm = 0; mm < AF; ++mm)
                #pragma unroll
                for (int nn = 0; nn < BF; ++nn)
                    acc[mm][nn] = __builtin_amdgcn_mfma_f32_16x16x32_bf16(
                        aF[mm], bF[nn], acc[mm][nn], 0, 0, 0);
            __builtin_amdgcn_s_setprio(0);
        }

        // gate: A(t+1) + B(t+1) landed; B(t+2)'s 3 stay in flight
        if (t + 2 < NT)      { vmcnt_wait<3>(); }
        else if (t + 1 < NT) { vmcnt_wait<0>(); }
    }

    // epilogue: bf16 out. C/D layout col=lane&15, row=(lane>>4)*4+reg
    const int crow = m0 + wm * 64 + fq * 4;
    const int ccol = n0 + wn * 48 + fr;
    #pragma unroll
    for (int m = 0; m < AF; m++)
        #pragma unroll
        for (int n = 0; n < BF; n++)
            #pragma unroll
            for (int rr = 0; rr < 4; rr++)
                C[(size_t)(crow + m*16 + rr) * QKV_N + ccol + n*16] = f2b(acc[m][n][rr]);
}

// ===========================================================================
// GEMM2: m201-style 8-phase schedule (round-12, kept).
//   out[4096,4096] = attnb @ WoT^T, K=1024. 256x256 tile, BK=64, grid 256.
// ===========================================================================
#define G2_BUF 32768   // shorts per buffer (64 KiB)

__global__ __launch_bounds__(512, 2)
void gemm2_8p(const unsigned short* __restrict__ A,
              const unsigned short* __restrict__ Bt,
              float* __restrict__ C) {
    constexpr int K     = O_N;        // 1024
    constexpr int N     = HID;        // 4096
    constexpr int NT    = K / 64;     // 16
    constexpr int NITER = NT / 2;     // 8

    __shared__ unsigned short smem[2 * G2_BUF];   // 128 KiB

    const int tid  = threadIdx.x;
    const int lane = tid & 63;
    const int wave = tid >> 6;
    const int wm   = wave >> 2;       // 0..1  (128 rows)
    const int wn   = wave & 3;        // 0..3  (64 cols)
    const int fr   = lane & 15;
    const int fq   = lane >> 4;

    const int nbx = N >> 8;           // 16
    int bid = blockIdx.x;
    const int cpx = gridDim.x >> 3;
    bid = (bid & 7) * cpx + (bid >> 3);
    const int bx = bid % nbx, by = bid / nbx;
    const int m0 = by << 8, n0 = bx << 8;

    const int srow = tid >> 3;
    const int scs  = ((tid & 7) ^ (srow & 7)) << 3;
    const unsigned short* gA = A  + (size_t)(m0 + srow) * K + scs;
    const unsigned short* gB = Bt + (size_t)(n0 + srow) * K + scs;
    const int frsw = fr & 7;

    f32x4_t acc[8][4];
    #pragma unroll
    for (int m = 0; m < 8; m++)
        #pragma unroll
        for (int n = 0; n < 4; n++)
            acc[m][n] = (f32x4_t){0.f, 0.f, 0.f, 0.f};

#define SA(T, q) gload_lds16(gA + (size_t)((q)*64)*K + (size_t)(T)*64, \
                             &smem[((T)&1)*G2_BUF + (q)*4096 + tid*8])
#define SB(T, q) gload_lds16(gB + (size_t)((q)*64)*K + (size_t)(T)*64, \
                             &smem[((T)&1)*G2_BUF + 16384 + (q)*4096 + tid*8])
#define RDA(T, MH, KI) { _Pragma("unroll") for (int mm = 0; mm < 4; ++mm) { \
    const int ro = ((T)&1)*G2_BUF + (wm*128 + (MH)*64 + mm*16 + fr)*64; \
    aF[mm] = *(const bf16x8_t*)&smem[ro + ((((KI)*4 + fq) ^ frsw) << 3)]; } }
#define RDB(T, KI, dst) { _Pragma("unroll") for (int nn = 0; nn < 4; ++nn) { \
    const int ro = ((T)&1)*G2_BUF + 16384 + (wn*64 + nn*16 + fr)*64; \
    dst[nn] = *(const bf16x8_t*)&smem[ro + ((((KI)*4 + fq) ^ frsw) << 3)]; } }
#define MM16(MH, BS) { __builtin_amdgcn_s_setprio(1); \
    _Pragma("unroll") for (int mm = 0; mm < 4; ++mm) \
    _Pragma("unroll") for (int nn = 0; nn < 4; ++nn) \
        acc[(MH)*4 + mm][nn] = __builtin_amdgcn_mfma_f32_16x16x32_bf16( \
            aF[mm], BS[nn], acc[(MH)*4 + mm][nn], 0, 0, 0); \
    __builtin_amdgcn_s_setprio(0); }

    SA(0,0); SA(0,1); SA(0,2); SA(0,3);
    SB(0,0); SB(0,1); SB(0,2); SB(0,3);
    SA(1,0); SA(1,2); SB(1,0); SB(1,1);
    vmcnt_wait<4>();
    BARF();

    for (int i = 0; i < NITER; ++i) {
        const int t0 = 2*i, t1 = 2*i + 1;
        bf16x8_t aF[4], b0[4], b1[4];

        RDA(t0, 0, 0); RDB(t0, 0, b0);
        SA(t1, 1); SA(t1, 3);
        BARF(); LGKMW(); MM16(0, b0); BARF();

        RDA(t0, 0, 1); RDB(t0, 1, b1);
        SB(t1, 2); SB(t1, 3);
        BARF(); LGKMW(); MM16(0, b1); BARF();

        RDA(t0, 1, 0);
        if (t0 + 2 < NT) { SA(t0 + 2, 0); SA(t0 + 2, 2); }
        BARF(); LGKMW(); MM16(1, b0); BARF();

        RDA(t0, 1, 1);
        if (t0 + 2 < NT) { SB(t0 + 2, 0); SB(t0 + 2, 1); }
        BARF(); LGKMW(); MM16(1, b1);
        if (i + 1 < NITER) { vmcnt_wait<4>(); } else { vmcnt_wait<0>(); }
        BARF();

        RDA(t1, 0, 0); RDB(t1, 0, b0);
        if (t0 + 2 < NT) { SA(t0 + 2, 1); SA(t0 + 2, 3); }
        BARF(); LGKMW(); MM16(0, b0); BARF();

        RDA(t1, 0, 1); RDB(t1, 1, b1);
        if (t0 + 2 < NT) { SB(t0 + 2, 2); SB(t0 + 2, 3); }
        BARF(); LGKMW(); MM16(0, b1); BARF();

        RDA(t1, 1, 0);
        if (t1 + 2 < NT) { SA(t1 + 2, 0); SA(t1 + 2, 2); }
        BARF(); LGKMW(); MM16(1, b0); BARF();

        RDA(t1, 1, 1);
        if (t1 + 2 < NT) { SB(t1 + 2, 0); SB(t1 + 2, 1); }
        BARF(); LGKMW(); MM16(1, b1);
        if (i + 1 < NITER) { vmcnt_wait<4>(); }
        BARF();
    }
#undef SA
#undef SB
#undef RDA
#undef RDB
#undef MM16

    const int crow = m0 + wm * 128 + fq * 4;
    const int ccol = n0 + wn * 64 + fr;
    #pragma unroll
    for (int m = 0; m < 8; m++)
        #pragma unroll
        for (int n = 0; n < 4; n++)
            #pragma unroll
            for (int rr = 0; rr < 4; rr++)
                C[(size_t)(crow + m*16 + rr) * N + ccol + n*16] = acc[m][n][rr];
}

// --------- fused RMSNorm + RoPE + 16-token block-diagonal attention --------
__global__ __launch_bounds__(64) void attn_fused(const unsigned short* __restrict__ qkv,
                                                 const float* __restrict__ cosb,
                                                 const float* __restrict__ sinb,
                                                 const float* __restrict__ qw,
                                                 const float* __restrict__ kw,
                                                 unsigned short* __restrict__ out) {
    const int h    = blockIdx.x & (NH - 1);
    const int blk  = (blockIdx.x >> 4) & 127;
    const int b    = blockIdx.x >> 11;
    const int pos0 = blk * 16;
    const int kvh  = h >> 2;

    const int lane = threadIdx.x;
    const int r    = lane >> 2;
    const int qp   = lane & 3;
    const int d0   = qp * 16;

    __shared__ float qs[16][65];
    __shared__ float ks[16][65];
    __shared__ float vs[16][65];
    __shared__ float ps[16][17];

    const size_t rowb = ((size_t)(b * L_SEQ + pos0 + r)) * NQKV;
    const unsigned short* qptr = qkv + (rowb + h) * HD + d0;
    const unsigned short* kptr = qkv + (rowb + NH + kvh) * HD + d0;
    const unsigned short* vptr = qkv + (rowb + NH + NKV + kvh) * HD + d0;
    const size_t csrow = ((size_t)(b * L_SEQ + pos0 + r)) * HD + d0;

    float q[16], k[16], v[16], cs[16], sn[16];
    {
        ushort8_t q0 = *(const ushort8_t*)&qptr[0], q1 = *(const ushort8_t*)&qptr[8];
        ushort8_t k0 = *(const ushort8_t*)&kptr[0], k1 = *(const ushort8_t*)&kptr[8];
        ushort8_t v0 = *(const ushort8_t*)&vptr[0], v1 = *(const ushort8_t*)&vptr[8];
        #pragma unroll
        for (int i = 0; i < 8; i++) {
            q[i] = b2f(q0[i]); q[i+8] = b2f(q1[i]);
            k[i] = b2f(k0[i]); k[i+8] = b2f(k1[i]);
            v[i] = b2f(v0[i]); v[i+8] = b2f(v1[i]);
        }
        #pragma unroll
        for (int i = 0; i < 16; i += 4) {
            *(float4*)&cs[i] = *(const float4*)&cosb[csrow + i];
            *(float4*)&sn[i] = *(const float4*)&sinb[csrow + i];
        }
    }

    float sq = 0.f, sk = 0.f;
    #pragma unroll
    for (int i = 0; i < 16; i++) { sq += q[i]*q[i]; sk += k[i]*k[i]; }
    sq += __shfl_xor(sq, 1); sq += __shfl_xor(sq, 2);
    sk += __shfl_xor(sk, 1); sk += __shfl_xor(sk, 2);
    const float rq = rsqrtf(sq * (1.f / HD) + EPSV);
    const float rk = rsqrtf(sk * (1.f / HD) + EPSV);

    const float sgn = (qp < 2) ? -1.f : 1.f;
    #pragma unroll
    for (int i = 0; i < 16; i++) {
        float qn = q[i] * rq * qw[d0 + i];
        float kn = k[i] * rk * kw[d0 + i];
        float qo = __shfl_xor(qn, 2);
        float ko = __shfl_xor(kn, 2);
        qs[r][d0 + i] = qn * cs[i] + sgn * qo * sn[i];
        ks[r][d0 + i] = kn * cs[i] + sgn * ko * sn[i];
        vs[r][d0 + i] = v[i];
    }
    __syncthreads();

    float sc[4] = {0.f, 0.f, 0.f, 0.f};
    for (int d = 0; d < 64; d++) {
        const float qd = qs[r][d];
        sc[0] += qd * ks[qp     ][d];
        sc[1] += qd * ks[qp +  4][d];
        sc[2] += qd * ks[qp +  8][d];
        sc[3] += qd * ks[qp + 12][d];
    }
    #pragma unroll
    for (int cc = 0; cc < 4; cc++) {
        const int c = qp + cc * 4;
        sc[cc] = (c <= r) ? sc[cc] * 0.125f : -3.0e38f;
    }
    float mx = fmaxf(fmaxf(sc[0], sc[1]), fmaxf(sc[2], sc[3]));
    mx = fmaxf(mx, __shfl_xor(mx, 1));
    mx = fmaxf(mx, __shfl_xor(mx, 2));
    float e[4], sum = 0.f;
    #pragma unroll
    for (int cc = 0; cc < 4; cc++) { e[cc] = __expf(sc[cc] - mx); sum += e[cc]; }
    sum += __shfl_xor(sum, 1); sum += __shfl_xor(sum, 2);
    const float inv = 1.f / sum;
    #pragma unroll
    for (int cc = 0; cc < 4; cc++) ps[r][qp + cc * 4] = e[cc] * inv;
    __syncthreads();

    float o[16];
    #pragma unroll
    for (int i = 0; i < 16; i++) o[i] = 0.f;
    #pragma unroll
    for (int c = 0; c < 16; c++) {
        const float p = ps[r][c];
        #pragma unroll
        for (int i = 0; i < 16; i++) o[i] += p * vs[c][d0 + i];
    }

    __attribute__((aligned(16))) unsigned short ob[16];
    #pragma unroll
    for (int i = 0; i < 16; i++) ob[i] = f2b(o[i]);
    unsigned short* optr = out + (((size_t)(b * L_SEQ + pos0 + r) * NH + h) * HD) + d0;
    *(uint4*)optr       = *(uint4*)&ob[0];
    *((uint4*)optr + 1) = *(uint4*)&ob[8];
}

// ---------------------------------------------------------------------------
extern "C" void kernel_launch(void* const* d_in, const int* in_sizes, int n_in,
                              void* d_out, int out_size, void* d_ws, size_t ws_size,
                              hipStream_t stream) {
    const float* hid  = (const float*)d_in[0];
    const float* cosb = (const float*)d_in[2];
    const float* sinb = (const float*)d_in[3];
    const float* Wqkv = (const float*)d_in[4];
    const float* Wo   = (const float*)d_in[5];
    const float* qw   = (const float*)d_in[6];
    const float* kw   = (const float*)d_in[7];
    float* outp = (float*)d_out;

    char* ws = (char*)d_ws;
    unsigned short* WqkvT = (unsigned short*)ws; ws += (size_t)QKV_N * HID * 2;
    unsigned short* WoT   = (unsigned short*)ws; ws += (size_t)HID * O_N * 2;
    unsigned short* qkvb  = (unsigned short*)ws; ws += (size_t)M_ROWS * QKV_N * 2;
    unsigned short* attnb = (unsigned short*)ws;

    // merged weight transposes
    transpose_both<<<dim3(6144 + 4096), 256, 0, stream>>>(Wqkv, WqkvT, Wo, WoT);

    // GEMM1 with fused fp32->bf16 A conversion (FIXED 16B-granular A swizzle)
    gemm1_af32<<<dim3((M_ROWS / 128) * (QKV_N / 192)), 512, 0, stream>>>
        (hid, WqkvT, qkvb);

    // fused rmsnorm + rope + block-diag attention (bf16 in/out)
    attn_fused<<<dim3(B_SZ * (L_SEQ / 16) * NH), 64, 0, stream>>>(qkvb, cosb, sinb, qw, kw, attnb);

    // GEMM2 (8-phase, kept from round 12)
    gemm2_8p<<<dim3((M_ROWS / 256) * (HID / 256)), 512, 0, stream>>>
        (attnb, WoT, outp);
}

// Round 15
// 142.574 us; speedup vs baseline: 1.8333x; 1.0986x over previous
//
#include <hip/hip_runtime.h>
#include <hip/hip_bf16.h>
#include <cstdint>

// Problem constants (from reference)
#define B_SZ   2
#define L_SEQ  2048
#define HID    4096
#define NH     16
#define NKV    4
#define HD     64
#define NQKV   (NH + 2*NKV)      // 24
#define QKV_N  (NQKV*HD)         // 1536
#define O_N    (NH*HD)           // 1024
#define M_ROWS (B_SZ*L_SEQ)      // 4096
#define EPSV   1e-6f

typedef __bf16  bf16x8_t  __attribute__((ext_vector_type(8)));
typedef float   f32x4_t   __attribute__((ext_vector_type(4)));
typedef unsigned short ushort8_t __attribute__((ext_vector_type(8)));

__device__ __forceinline__ unsigned short f2b(float f) {
    union { float f; uint32_t u; } v; v.f = f;
    uint32_t r = v.u + 0x7FFFu + ((v.u >> 16) & 1u);   // RNE to bf16
    return (unsigned short)(r >> 16);
}
__device__ __forceinline__ float b2f(unsigned short u) {
    union { uint32_t u; float f; } v; v.u = ((uint32_t)u) << 16;
    return v.f;
}

__device__ __forceinline__ void gload_lds16(const void* g, void* l) {
    __builtin_amdgcn_global_load_lds(
        (__attribute__((address_space(1))) void*)(g),
        (__attribute__((address_space(3))) void*)(l),
        16, 0, 0);
}

#define BARF() do { asm volatile("" ::: "memory"); \
                    __builtin_amdgcn_s_barrier();  \
                    asm volatile("" ::: "memory"); } while (0)
#define LGKMW() asm volatile("s_waitcnt lgkmcnt(0)" ::: "memory")

template <int N> __device__ __forceinline__ void vmcnt_wait() {
    if constexpr (N == 4)       asm volatile("s_waitcnt vmcnt(4)"  ::: "memory");
    else if constexpr (N == 5)  asm volatile("s_waitcnt vmcnt(5)"  ::: "memory");
    else if constexpr (N == 6)  asm volatile("s_waitcnt vmcnt(6)"  ::: "memory");
    else if constexpr (N == 8)  asm volatile("s_waitcnt vmcnt(8)"  ::: "memory");
    else if constexpr (N == 12) asm volatile("s_waitcnt vmcnt(12)" ::: "memory");
    else                        asm volatile("s_waitcnt vmcnt(0)"  ::: "memory");
}

// ===========================================================================
// prep: ONE launch doing (a) hid fp32->bf16 cvt (blocks 0..8191) and
// (b) both weight transposes fp32(RxC) -> bf16(CxR) (blocks 8192..18431).
// Merging saves one kernel launch + inter-kernel pipeline drain.
// ===========================================================================
#define CVT_BLKS 8192            // (M_ROWS*HID/8) / 256
__global__ __launch_bounds__(256) void prep(const float* __restrict__ hid,
                                            unsigned short* __restrict__ Hb,
                                            const float* __restrict__ Wqkv,
                                            unsigned short* __restrict__ WqkvT,
                                            const float* __restrict__ Wo,
                                            unsigned short* __restrict__ WoT) {
    if (blockIdx.x < CVT_BLKS) {
        // ---- cvt: 8 elems/thread, vectorized ----
        int i = blockIdx.x * 256 + threadIdx.x;
        const float4* p = (const float4*)(hid + (size_t)i * 8);
        float4 a = p[0], b = p[1];
        ushort8_t o;
        o[0]=f2b(a.x); o[1]=f2b(a.y); o[2]=f2b(a.z); o[3]=f2b(a.w);
        o[4]=f2b(b.x); o[5]=f2b(b.y); o[6]=f2b(b.z); o[7]=f2b(b.w);
        *(ushort8_t*)(Hb + (size_t)i * 8) = o;
        return;
    }
    // ---- transposes ----
    __shared__ float t[32][33];
    const float* in;
    unsigned short* out;
    int R, C, bx, by;
    int blk = blockIdx.x - CVT_BLKS;
    if (blk < 6144) {
        in = Wqkv; out = WqkvT; R = HID; C = QKV_N;
        bx = blk % 48; by = blk / 48;
    } else {
        blk -= 6144;
        in = Wo; out = WoT; R = O_N; C = HID;
        bx = blk % 128; by = blk / 128;
    }
    const int c0 = bx * 32;
    const int r0 = by * 32;
    const int tx = threadIdx.x & 31;
    const int ty = threadIdx.x >> 5;
    #pragma unroll
    for (int i = 0; i < 32; i += 8)
        t[ty + i][tx] = in[(size_t)(r0 + ty + i) * C + c0 + tx];
    __syncthreads();
    #pragma unroll
    for (int i = 0; i < 32; i += 8)
        out[(size_t)(c0 + ty + i) * R + r0 + tx] = f2b(t[tx][ty + i]);
}

// ===========================================================================
// Single-barrier multi-buffered MFMA GEMM template (round-6 proven; G1).
//   C[M,N] = A[M,K] * Bt[N,K]^T, bf16 in, OutT out.
//   8 waves as NWM x NWN, one barrier + one counted vmcnt per K-tile.
//   NBUF LDS buffers; stage(t+NBUF-1) issued during tile t.
//   T2 swizzle: BK=64 -> chunk^(row&7), both-sides involution.
// ===========================================================================
template <int BM, int BN, int BK, int NBUF, int NWM, int NWN, bool OBF16, typename OutT>
__global__ __launch_bounds__(512, 2)
void gemm_sb(const unsigned short* __restrict__ A,
             const unsigned short* __restrict__ Bt,
             OutT* __restrict__ C, int M, int N, int K) {
    constexpr int WM    = BM / NWM;
    constexpr int WN    = BN / NWN;
    constexpr int AF    = WM / 16;
    constexpr int BF    = WN / 16;
    constexpr int KK    = BK / 32;
    constexpr int BUF   = (BM + BN) * BK;
    constexpr int ROWS  = 4096 / BK;
    constexpr int AR    = BM / ROWS;
    constexpr int BR    = BN / ROWS;
    constexpr int RNDS  = AR + BR;
    constexpr int DEPTH = NBUF - 2;

    __shared__ unsigned short smem[NBUF * BUF];

    const int tid  = threadIdx.x;
    const int lane = tid & 63;
    const int wave = tid >> 6;
    const int wm   = wave / NWN;
    const int wn   = wave % NWN;
    const int fr   = lane & 15;
    const int fq   = lane >> 4;

    const int nbx = N / BN;
    int bid = blockIdx.x;
    const int cpx = gridDim.x >> 3;
    bid = (bid & 7) * cpx + (bid >> 3);
    const int bx = bid % nbx, by = bid / nbx;
    const int m0 = by * BM, n0 = bx * BN;

    const int srow = tid / (BK / 8);
    const int sch  = tid & (BK / 8 - 1);
    const int ssw  = (BK == 64) ? (srow & 7) : ((srow >> 1) & 3);
    const int scs  = (sch ^ ssw) << 3;
    const unsigned short* gA = A  + (size_t)(m0 + srow) * K + scs;
    const unsigned short* gB = Bt + (size_t)(n0 + srow) * K + scs;

    const int frsw = (BK == 64) ? (fr & 7) : ((fr >> 1) & 3);

    f32x4_t acc[AF][BF];
    #pragma unroll
    for (int m = 0; m < AF; m++)
        #pragma unroll
        for (int n = 0; n < BF; n++)
            acc[m][n] = (f32x4_t){0.f, 0.f, 0.f, 0.f};

    const int NT = K / BK;

    auto STAGE = [&](int T) {
        const int pb = (T % NBUF) * BUF;
        #pragma unroll
        for (int q = 0; q < AR; ++q)
            gload_lds16(gA + (size_t)(q * ROWS) * K + (size_t)T * BK,
                        &smem[pb + q * 4096 + tid * 8]);
        #pragma unroll
        for (int q = 0; q < BR; ++q)
            gload_lds16(gB + (size_t)(q * ROWS) * K + (size_t)T * BK,
                        &smem[pb + BM * BK + q * 4096 + tid * 8]);
    };

    #pragma unroll
    for (int pt = 0; pt < NBUF - 1; ++pt) STAGE(pt);
    vmcnt_wait<DEPTH * RNDS>();

    for (int t = 0; t < NT; ++t) {
        const int sb = (t % NBUF) * BUF;
        BARF();   // the ONLY barrier per tile

        #pragma unroll
        for (int kk = 0; kk < KK; ++kk) {
            const int cxk = (((kk * 4 + fq) ^ frsw)) << 3;
            bf16x8_t aF[AF], bF[BF];
            #pragma unroll
            for (int mm = 0; mm < AF; ++mm)
                aF[mm] = *(const bf16x8_t*)&smem[sb + (wm*WM + mm*16 + fr)*BK + cxk];
            #pragma unroll
            for (int nn = 0; nn < BF; ++nn)
                bF[nn] = *(const bf16x8_t*)&smem[sb + BM*BK + (wn*WN + nn*16 + fr)*BK + cxk];

            if (kk == 0 && t + NBUF - 1 < NT) STAGE(t + NBUF - 1);

            __builtin_amdgcn_s_setprio(1);
            #pragma unroll
            for (int mm = 0; mm < AF; ++mm)
                #pragma unroll
                for (int nn = 0; nn < BF; ++nn)
                    acc[mm][nn] = __builtin_amdgcn_mfma_f32_16x16x32_bf16(
                        aF[mm], bF[nn], acc[mm][nn], 0, 0, 0);
            __builtin_amdgcn_s_setprio(0);
        }

        if constexpr (DEPTH == 2) {
            if (t + 3 < NT)      { vmcnt_wait<2 * RNDS>(); }
            else if (t + 2 < NT) { vmcnt_wait<RNDS>(); }
            else if (t + 1 < NT) { vmcnt_wait<0>(); }
        } else {
            if (t + 2 < NT)      { vmcnt_wait<RNDS>(); }
            else if (t + 1 < NT) { vmcnt_wait<0>(); }
        }
    }

    // C/D layout (m89-verified): col = lane&15, row = (lane>>4)*4 + reg
    const int crow = m0 + wm * WM + fq * 4;
    const int ccol = n0 + wn * WN + fr;
    #pragma unroll
    for (int m = 0; m < AF; m++)
        #pragma unroll
        for (int n = 0; n < BF; n++)
            #pragma unroll
            for (int rr = 0; rr < 4; rr++) {
                const size_t idx = (size_t)(crow + m*16 + rr) * N + ccol + n*16;
                if constexpr (OBF16) C[idx] = (OutT)f2b(acc[m][n][rr]);
                else                 C[idx] = (OutT)acc[m][n][rr];
            }
}

// ===========================================================================
// GEMM2: m201-style 8-phase schedule (round-12 proven).
//   out[4096,4096] = attnb @ WoT^T, K=1024. 256x256 tile, BK=64, grid 256.
// ===========================================================================
#define G2_BUF 32768   // shorts per buffer (64 KiB)

__global__ __launch_bounds__(512, 2)
void gemm2_8p(const unsigned short* __restrict__ A,
              const unsigned short* __restrict__ Bt,
              float* __restrict__ C) {
    constexpr int K     = O_N;        // 1024
    constexpr int N     = HID;        // 4096
    constexpr int NT    = K / 64;     // 16
    constexpr int NITER = NT / 2;     // 8

    __shared__ unsigned short smem[2 * G2_BUF];   // 128 KiB

    const int tid  = threadIdx.x;
    const int lane = tid & 63;
    const int wave = tid >> 6;
    const int wm   = wave >> 2;       // 0..1  (128 rows)
    const int wn   = wave & 3;        // 0..3  (64 cols)
    const int fr   = lane & 15;
    const int fq   = lane >> 4;

    const int nbx = N >> 8;           // 16
    int bid = blockIdx.x;
    const int cpx = gridDim.x >> 3;
    bid = (bid & 7) * cpx + (bid >> 3);
    const int bx = bid % nbx, by = bid / nbx;
    const int m0 = by << 8, n0 = bx << 8;

    const int srow = tid >> 3;
    const int scs  = ((tid & 7) ^ (srow & 7)) << 3;
    const unsigned short* gA = A  + (size_t)(m0 + srow) * K + scs;
    const unsigned short* gB = Bt + (size_t)(n0 + srow) * K + scs;
    const int frsw = fr & 7;

    f32x4_t acc[8][4];
    #pragma unroll
    for (int m = 0; m < 8; m++)
        #pragma unroll
        for (int n = 0; n < 4; n++)
            acc[m][n] = (f32x4_t){0.f, 0.f, 0.f, 0.f};

#define SA(T, q) gload_lds16(gA + (size_t)((q)*64)*K + (size_t)(T)*64, \
                             &smem[((T)&1)*G2_BUF + (q)*4096 + tid*8])
#define SB(T, q) gload_lds16(gB + (size_t)((q)*64)*K + (size_t)(T)*64, \
                             &smem[((T)&1)*G2_BUF + 16384 + (q)*4096 + tid*8])
#define RDA(T, MH, KI) { _Pragma("unroll") for (int mm = 0; mm < 4; ++mm) { \
    const int ro = ((T)&1)*G2_BUF + (wm*128 + (MH)*64 + mm*16 + fr)*64; \
    aF[mm] = *(const bf16x8_t*)&smem[ro + ((((KI)*4 + fq) ^ frsw) << 3)]; } }
#define RDB(T, KI, dst) { _Pragma("unroll") for (int nn = 0; nn < 4; ++nn) { \
    const int ro = ((T)&1)*G2_BUF + 16384 + (wn*64 + nn*16 + fr)*64; \
    dst[nn] = *(const bf16x8_t*)&smem[ro + ((((KI)*4 + fq) ^ frsw) << 3)]; } }
#define MM16(MH, BS) { __builtin_amdgcn_s_setprio(1); \
    _Pragma("unroll") for (int mm = 0; mm < 4; ++mm) \
    _Pragma("unroll") for (int nn = 0; nn < 4; ++nn) \
        acc[(MH)*4 + mm][nn] = __builtin_amdgcn_mfma_f32_16x16x32_bf16( \
            aF[mm], BS[nn], acc[(MH)*4 + mm][nn], 0, 0, 0); \
    __builtin_amdgcn_s_setprio(0); }

    SA(0,0); SA(0,1); SA(0,2); SA(0,3);
    SB(0,0); SB(0,1); SB(0,2); SB(0,3);
    SA(1,0); SA(1,2); SB(1,0); SB(1,1);
    vmcnt_wait<4>();
    BARF();

    for (int i = 0; i < NITER; ++i) {
        const int t0 = 2*i, t1 = 2*i + 1;
        bf16x8_t aF[4], b0[4], b1[4];

        RDA(t0, 0, 0); RDB(t0, 0, b0);
        SA(t1, 1); SA(t1, 3);
        BARF(); LGKMW(); MM16(0, b0); BARF();

        RDA(t0, 0, 1); RDB(t0, 1, b1);
        SB(t1, 2); SB(t1, 3);
        BARF(); LGKMW(); MM16(0, b1); BARF();

        RDA(t0, 1, 0);
        if (t0 + 2 < NT) { SA(t0 + 2, 0); SA(t0 + 2, 2); }
        BARF(); LGKMW(); MM16(1, b0); BARF();

        RDA(t0, 1, 1);
        if (t0 + 2 < NT) { SB(t0 + 2, 0); SB(t0 + 2, 1); }
        BARF(); LGKMW(); MM16(1, b1);
        if (i + 1 < NITER) { vmcnt_wait<4>(); } else { vmcnt_wait<0>(); }
        BARF();

        RDA(t1, 0, 0); RDB(t1, 0, b0);
        if (t0 + 2 < NT) { SA(t0 + 2, 1); SA(t0 + 2, 3); }
        BARF(); LGKMW(); MM16(0, b0); BARF();

        RDA(t1, 0, 1); RDB(t1, 1, b1);
        if (t0 + 2 < NT) { SB(t0 + 2, 2); SB(t0 + 2, 3); }
        BARF(); LGKMW(); MM16(0, b1); BARF();

        RDA(t1, 1, 0);
        if (t1 + 2 < NT) { SA(t1 + 2, 0); SA(t1 + 2, 2); }
        BARF(); LGKMW(); MM16(1, b0); BARF();

        RDA(t1, 1, 1);
        if (t1 + 2 < NT) { SB(t1 + 2, 0); SB(t1 + 2, 1); }
        BARF(); LGKMW(); MM16(1, b1);
        if (i + 1 < NITER) { vmcnt_wait<4>(); }
        BARF();
    }
#undef SA
#undef SB
#undef RDA
#undef RDB
#undef MM16

    const int crow = m0 + wm * 128 + fq * 4;
    const int ccol = n0 + wn * 64 + fr;
    #pragma unroll
    for (int m = 0; m < 8; m++)
        #pragma unroll
        for (int n = 0; n < 4; n++)
            #pragma unroll
            for (int rr = 0; rr < 4; rr++)
                C[(size_t)(crow + m*16 + rr) * N + ccol + n*16] = acc[m][n][rr];
}

// --------- fused RMSNorm + RoPE + 16-token block-diagonal attention --------
__global__ __launch_bounds__(64) void attn_fused(const unsigned short* __restrict__ qkv,
                                                 const float* __restrict__ cosb,
                                                 const float* __restrict__ sinb,
                                                 const float* __restrict__ qw,
                                                 const float* __restrict__ kw,
                                                 unsigned short* __restrict__ out) {
    const int h    = blockIdx.x & (NH - 1);
    const int blk  = (blockIdx.x >> 4) & 127;
    const int b    = blockIdx.x >> 11;
    const int pos0 = blk * 16;
    const int kvh  = h >> 2;

    const int lane = threadIdx.x;
    const int r    = lane >> 2;
    const int qp   = lane & 3;
    const int d0   = qp * 16;

    __shared__ float qs[16][65];
    __shared__ float ks[16][65];
    __shared__ float vs[16][65];
    __shared__ float ps[16][17];

    const size_t rowb = ((size_t)(b * L_SEQ + pos0 + r)) * NQKV;
    const unsigned short* qptr = qkv + (rowb + h) * HD + d0;
    const unsigned short* kptr = qkv + (rowb + NH + kvh) * HD + d0;
    const unsigned short* vptr = qkv + (rowb + NH + NKV + kvh) * HD + d0;
    const size_t csrow = ((size_t)(b * L_SEQ + pos0 + r)) * HD + d0;

    float q[16], k[16], v[16], cs[16], sn[16];
    {
        ushort8_t q0 = *(const ushort8_t*)&qptr[0], q1 = *(const ushort8_t*)&qptr[8];
        ushort8_t k0 = *(const ushort8_t*)&kptr[0], k1 = *(const ushort8_t*)&kptr[8];
        ushort8_t v0 = *(const ushort8_t*)&vptr[0], v1 = *(const ushort8_t*)&vptr[8];
        #pragma unroll
        for (int i = 0; i < 8; i++) {
            q[i] = b2f(q0[i]); q[i+8] = b2f(q1[i]);
            k[i] = b2f(k0[i]); k[i+8] = b2f(k1[i]);
            v[i] = b2f(v0[i]); v[i+8] = b2f(v1[i]);
        }
        #pragma unroll
        for (int i = 0; i < 16; i += 4) {
            *(float4*)&cs[i] = *(const float4*)&cosb[csrow + i];
            *(float4*)&sn[i] = *(const float4*)&sinb[csrow + i];
        }
    }

    float sq = 0.f, sk = 0.f;
    #pragma unroll
    for (int i = 0; i < 16; i++) { sq += q[i]*q[i]; sk += k[i]*k[i]; }
    sq += __shfl_xor(sq, 1); sq += __shfl_xor(sq, 2);
    sk += __shfl_xor(sk, 1); sk += __shfl_xor(sk, 2);
    const float rq = rsqrtf(sq * (1.f / HD) + EPSV);
    const float rk = rsqrtf(sk * (1.f / HD) + EPSV);

    const float sgn = (qp < 2) ? -1.f : 1.f;
    #pragma unroll
    for (int i = 0; i < 16; i++) {
        float qn = q[i] * rq * qw[d0 + i];
        float kn = k[i] * rk * kw[d0 + i];
        float qo = __shfl_xor(qn, 2);
        float ko = __shfl_xor(kn, 2);
        qs[r][d0 + i] = qn * cs[i] + sgn * qo * sn[i];
        ks[r][d0 + i] = kn * cs[i] + sgn * ko * sn[i];
        vs[r][d0 + i] = v[i];
    }
    __syncthreads();

    float sc[4] = {0.f, 0.f, 0.f, 0.f};
    for (int d = 0; d < 64; d++) {
        const float qd = qs[r][d];
        sc[0] += qd * ks[qp     ][d];
        sc[1] += qd * ks[qp +  4][d];
        sc[2] += qd * ks[qp +  8][d];
        sc[3] += qd * ks[qp + 12][d];
    }
    #pragma unroll
    for (int cc = 0; cc < 4; cc++) {
        const int c = qp + cc * 4;
        sc[cc] = (c <= r) ? sc[cc] * 0.125f : -3.0e38f;
    }
    float mx = fmaxf(fmaxf(sc[0], sc[1]), fmaxf(sc[2], sc[3]));
    mx = fmaxf(mx, __shfl_xor(mx, 1));
    mx = fmaxf(mx, __shfl_xor(mx, 2));
    float e[4], sum = 0.f;
    #pragma unroll
    for (int cc = 0; cc < 4; cc++) { e[cc] = __expf(sc[cc] - mx); sum += e[cc]; }
    sum += __shfl_xor(sum, 1); sum += __shfl_xor(sum, 2);
    const float inv = 1.f / sum;
    #pragma unroll
    for (int cc = 0; cc < 4; cc++) ps[r][qp + cc * 4] = e[cc] * inv;
    __syncthreads();

    float o[16];
    #pragma unroll
    for (int i = 0; i < 16; i++) o[i] = 0.f;
    #pragma unroll
    for (int c = 0; c < 16; c++) {
        const float p = ps[r][c];
        #pragma unroll
        for (int i = 0; i < 16; i++) o[i] += p * vs[c][d0 + i];
    }

    __attribute__((aligned(16))) unsigned short ob[16];
    #pragma unroll
    for (int i = 0; i < 16; i++) ob[i] = f2b(o[i]);
    unsigned short* optr = out + (((size_t)(b * L_SEQ + pos0 + r) * NH + h) * HD) + d0;
    *(uint4*)optr       = *(uint4*)&ob[0];
    *((uint4*)optr + 1) = *(uint4*)&ob[8];
}

// ---------------------------------------------------------------------------
extern "C" void kernel_launch(void* const* d_in, const int* in_sizes, int n_in,
                              void* d_out, int out_size, void* d_ws, size_t ws_size,
                              hipStream_t stream) {
    const float* hid  = (const float*)d_in[0];
    const float* cosb = (const float*)d_in[2];
    const float* sinb = (const float*)d_in[3];
    const float* Wqkv = (const float*)d_in[4];
    const float* Wo   = (const float*)d_in[5];
    const float* qw   = (const float*)d_in[6];
    const float* kw   = (const float*)d_in[7];
    float* outp = (float*)d_out;

    char* ws = (char*)d_ws;
    unsigned short* Hb    = (unsigned short*)ws; ws += (size_t)M_ROWS * HID * 2;
    unsigned short* WqkvT = (unsigned short*)ws; ws += (size_t)QKV_N * HID * 2;
    unsigned short* WoT   = (unsigned short*)ws; ws += (size_t)HID * O_N * 2;
    unsigned short* qkvb  = (unsigned short*)ws; ws += (size_t)M_ROWS * QKV_N * 2;
    unsigned short* attnb = (unsigned short*)ws;

    // prep: cvt (8192 blocks) + both transposes (10240 blocks) in ONE launch
    prep<<<dim3(CVT_BLKS + 6144 + 4096), 256, 0, stream>>>
        (hid, Hb, Wqkv, WqkvT, Wo, WoT);

    // GEMM1 (round-6/12 measured best): qkv = H @ Wqkv (4096 x 1536 x 4096)
    //   128x192 tiles, BK=64, NBUF=3 (120KB), 256 blocks (full coverage)
    gemm_sb<128, 192, 64, 3, 2, 4, true, unsigned short>
        <<<dim3((M_ROWS / 128) * (QKV_N / 192)), 512, 0, stream>>>
        (Hb, WqkvT, qkvb, M_ROWS, QKV_N, HID);

    // fused rmsnorm + rope + block-diag attention (bf16 in/out)
    attn_fused<<<dim3(B_SZ * (L_SEQ / 16) * NH), 64, 0, stream>>>(qkvb, cosb, sinb, qw, kw, attnb);

    // GEMM2 (round-12 measured best): 8-phase 256^2, grid 256
    gemm2_8p<<<dim3((M_ROWS / 256) * (HID / 256)), 512, 0, stream>>>
        (attnb, WoT, outp);
}

// Round 16
// 139.402 us; speedup vs baseline: 1.8750x; 1.0228x over previous
//
#include <hip/hip_runtime.h>
#include <hip/hip_bf16.h>
#include <cstdint>

// Problem constants (from reference)
#define B_SZ   2
#define L_SEQ  2048
#define HID    4096
#define NH     16
#define NKV    4
#define HD     64
#define NQKV   (NH + 2*NKV)      // 24
#define QKV_N  (NQKV*HD)         // 1536
#define O_N    (NH*HD)           // 1024
#define M_ROWS (B_SZ*L_SEQ)      // 4096
#define EPSV   1e-6f

typedef __bf16  bf16x8_t  __attribute__((ext_vector_type(8)));
typedef float   f32x4_t   __attribute__((ext_vector_type(4)));
typedef unsigned short ushort8_t __attribute__((ext_vector_type(8)));

__device__ __forceinline__ unsigned short f2b(float f) {
    union { float f; uint32_t u; } v; v.f = f;
    uint32_t r = v.u + 0x7FFFu + ((v.u >> 16) & 1u);   // RNE to bf16
    return (unsigned short)(r >> 16);
}
__device__ __forceinline__ float b2f(unsigned short u) {
    union { uint32_t u; float f; } v; v.u = ((uint32_t)u) << 16;
    return v.f;
}

__device__ __forceinline__ void gload_lds16(const void* g, void* l) {
    __builtin_amdgcn_global_load_lds(
        (__attribute__((address_space(1))) void*)(g),
        (__attribute__((address_space(3))) void*)(l),
        16, 0, 0);
}

#define BARF() do { asm volatile("" ::: "memory"); \
                    __builtin_amdgcn_s_barrier();  \
                    asm volatile("" ::: "memory"); } while (0)
#define LGKMW() asm volatile("s_waitcnt lgkmcnt(0)" ::: "memory")

template <int N> __device__ __forceinline__ void vmcnt_wait() {
    if constexpr (N == 4)       asm volatile("s_waitcnt vmcnt(4)"  ::: "memory");
    else if constexpr (N == 5)  asm volatile("s_waitcnt vmcnt(5)"  ::: "memory");
    else if constexpr (N == 6)  asm volatile("s_waitcnt vmcnt(6)"  ::: "memory");
    else if constexpr (N == 8)  asm volatile("s_waitcnt vmcnt(8)"  ::: "memory");
    else if constexpr (N == 12) asm volatile("s_waitcnt vmcnt(12)" ::: "memory");
    else                        asm volatile("s_waitcnt vmcnt(0)"  ::: "memory");
}

// ===========================================================================
// prep: ONE launch doing (a) hid fp32->bf16 cvt (blocks 0..8191) and
// (b) both weight transposes fp32(RxC) -> bf16(CxR) (blocks 8192..18431).
// ===========================================================================
#define CVT_BLKS 8192            // (M_ROWS*HID/8) / 256
__global__ __launch_bounds__(256) void prep(const float* __restrict__ hid,
                                            unsigned short* __restrict__ Hb,
                                            const float* __restrict__ Wqkv,
                                            unsigned short* __restrict__ WqkvT,
                                            const float* __restrict__ Wo,
                                            unsigned short* __restrict__ WoT) {
    if (blockIdx.x < CVT_BLKS) {
        int i = blockIdx.x * 256 + threadIdx.x;
        const float4* p = (const float4*)(hid + (size_t)i * 8);
        float4 a = p[0], b = p[1];
        ushort8_t o;
        o[0]=f2b(a.x); o[1]=f2b(a.y); o[2]=f2b(a.z); o[3]=f2b(a.w);
        o[4]=f2b(b.x); o[5]=f2b(b.y); o[6]=f2b(b.z); o[7]=f2b(b.w);
        *(ushort8_t*)(Hb + (size_t)i * 8) = o;
        return;
    }
    __shared__ float t[32][33];
    const float* in;
    unsigned short* out;
    int R, C, bx, by;
    int blk = blockIdx.x - CVT_BLKS;
    if (blk < 6144) {
        in = Wqkv; out = WqkvT; R = HID; C = QKV_N;
        bx = blk % 48; by = blk / 48;
    } else {
        blk -= 6144;
        in = Wo; out = WoT; R = O_N; C = HID;
        bx = blk % 128; by = blk / 128;
    }
    const int c0 = bx * 32;
    const int r0 = by * 32;
    const int tx = threadIdx.x & 31;
    const int ty = threadIdx.x >> 5;
    #pragma unroll
    for (int i = 0; i < 32; i += 8)
        t[ty + i][tx] = in[(size_t)(r0 + ty + i) * C + c0 + tx];
    __syncthreads();
    #pragma unroll
    for (int i = 0; i < 32; i += 8)
        out[(size_t)(c0 + ty + i) * R + r0 + tx] = f2b(t[tx][ty + i]);
}

// ===========================================================================
// Single-barrier multi-buffered MFMA GEMM template (round-6 proven; G1).
// ===========================================================================
template <int BM, int BN, int BK, int NBUF, int NWM, int NWN, bool OBF16, typename OutT>
__global__ __launch_bounds__(512, 2)
void gemm_sb(const unsigned short* __restrict__ A,
             const unsigned short* __restrict__ Bt,
             OutT* __restrict__ C, int M, int N, int K) {
    constexpr int WM    = BM / NWM;
    constexpr int WN    = BN / NWN;
    constexpr int AF    = WM / 16;
    constexpr int BF    = WN / 16;
    constexpr int KK    = BK / 32;
    constexpr int BUF   = (BM + BN) * BK;
    constexpr int ROWS  = 4096 / BK;
    constexpr int AR    = BM / ROWS;
    constexpr int BR    = BN / ROWS;
    constexpr int RNDS  = AR + BR;
    constexpr int DEPTH = NBUF - 2;

    __shared__ unsigned short smem[NBUF * BUF];

    const int tid  = threadIdx.x;
    const int lane = tid & 63;
    const int wave = tid >> 6;
    const int wm   = wave / NWN;
    const int wn   = wave % NWN;
    const int fr   = lane & 15;
    const int fq   = lane >> 4;

    const int nbx = N / BN;
    int bid = blockIdx.x;
    const int cpx = gridDim.x >> 3;
    bid = (bid & 7) * cpx + (bid >> 3);
    const int bx = bid % nbx, by = bid / nbx;
    const int m0 = by * BM, n0 = bx * BN;

    const int srow = tid / (BK / 8);
    const int sch  = tid & (BK / 8 - 1);
    const int ssw  = (BK == 64) ? (srow & 7) : ((srow >> 1) & 3);
    const int scs  = (sch ^ ssw) << 3;
    const unsigned short* gA = A  + (size_t)(m0 + srow) * K + scs;
    const unsigned short* gB = Bt + (size_t)(n0 + srow) * K + scs;

    const int frsw = (BK == 64) ? (fr & 7) : ((fr >> 1) & 3);

    f32x4_t acc[AF][BF];
    #pragma unroll
    for (int m = 0; m < AF; m++)
        #pragma unroll
        for (int n = 0; n < BF; n++)
            acc[m][n] = (f32x4_t){0.f, 0.f, 0.f, 0.f};

    const int NT = K / BK;

    auto STAGE = [&](int T) {
        const int pb = (T % NBUF) * BUF;
        #pragma unroll
        for (int q = 0; q < AR; ++q)
            gload_lds16(gA + (size_t)(q * ROWS) * K + (size_t)T * BK,
                        &smem[pb + q * 4096 + tid * 8]);
        #pragma unroll
        for (int q = 0; q < BR; ++q)
            gload_lds16(gB + (size_t)(q * ROWS) * K + (size_t)T * BK,
                        &smem[pb + BM * BK + q * 4096 + tid * 8]);
    };

    #pragma unroll
    for (int pt = 0; pt < NBUF - 1; ++pt) STAGE(pt);
    vmcnt_wait<DEPTH * RNDS>();

    for (int t = 0; t < NT; ++t) {
        const int sb = (t % NBUF) * BUF;
        BARF();   // the ONLY barrier per tile

        #pragma unroll
        for (int kk = 0; kk < KK; ++kk) {
            const int cxk = (((kk * 4 + fq) ^ frsw)) << 3;
            bf16x8_t aF[AF], bF[BF];
            #pragma unroll
            for (int mm = 0; mm < AF; ++mm)
                aF[mm] = *(const bf16x8_t*)&smem[sb + (wm*WM + mm*16 + fr)*BK + cxk];
            #pragma unroll
            for (int nn = 0; nn < BF; ++nn)
                bF[nn] = *(const bf16x8_t*)&smem[sb + BM*BK + (wn*WN + nn*16 + fr)*BK + cxk];

            if (kk == 0 && t + NBUF - 1 < NT) STAGE(t + NBUF - 1);

            __builtin_amdgcn_s_setprio(1);
            #pragma unroll
            for (int mm = 0; mm < AF; ++mm)
                #pragma unroll
                for (int nn = 0; nn < BF; ++nn)
                    acc[mm][nn] = __builtin_amdgcn_mfma_f32_16x16x32_bf16(
                        aF[mm], bF[nn], acc[mm][nn], 0, 0, 0);
            __builtin_amdgcn_s_setprio(0);
        }

        if constexpr (DEPTH == 2) {
            if (t + 3 < NT)      { vmcnt_wait<2 * RNDS>(); }
            else if (t + 2 < NT) { vmcnt_wait<RNDS>(); }
            else if (t + 1 < NT) { vmcnt_wait<0>(); }
        } else {
            if (t + 2 < NT)      { vmcnt_wait<RNDS>(); }
            else if (t + 1 < NT) { vmcnt_wait<0>(); }
        }
    }

    // C/D layout (m89-verified): col = lane&15, row = (lane>>4)*4 + reg
    const int crow = m0 + wm * WM + fq * 4;
    const int ccol = n0 + wn * WN + fr;
    #pragma unroll
    for (int m = 0; m < AF; m++)
        #pragma unroll
        for (int n = 0; n < BF; n++)
            #pragma unroll
            for (int rr = 0; rr < 4; rr++) {
                const size_t idx = (size_t)(crow + m*16 + rr) * N + ccol + n*16;
                if constexpr (OBF16) C[idx] = (OutT)f2b(acc[m][n][rr]);
                else                 C[idx] = (OutT)acc[m][n][rr];
            }
}

// ===========================================================================
// GEMM2: m201-style 8-phase schedule + NEW coalesced epilogue.
//   out[4096,4096] = attnb @ WoT^T, K=1024. 256x256 tile, BK=64, grid 256.
//   Epilogue: 2 passes over M-halves. Owning waves ds_write acc into the
//   (free, exactly 128KB) LDS as a 128x256 fp32 tile with XOR swizzle
//   col ^= (row&7)<<2 (write-side <=2-way; read-side each row is a full
//   bank permutation). All 8 waves then read one row per slot and store
//   global_store_dwordx4, 1KB contiguous per instruction.
// ===========================================================================
#define G2_BUF 32768   // shorts per buffer (64 KiB)

__global__ __launch_bounds__(512, 2)
void gemm2_8p(const unsigned short* __restrict__ A,
              const unsigned short* __restrict__ Bt,
              float* __restrict__ C) {
    constexpr int K     = O_N;        // 1024
    constexpr int N     = HID;        // 4096
    constexpr int NT    = K / 64;     // 16
    constexpr int NITER = NT / 2;     // 8

    __shared__ unsigned short smem[2 * G2_BUF];   // 128 KiB

    const int tid  = threadIdx.x;
    const int lane = tid & 63;
    const int wave = tid >> 6;
    const int wm   = wave >> 2;       // 0..1  (128 rows)
    const int wn   = wave & 3;        // 0..3  (64 cols)
    const int fr   = lane & 15;
    const int fq   = lane >> 4;

    const int nbx = N >> 8;           // 16
    int bid = blockIdx.x;
    const int cpx = gridDim.x >> 3;
    bid = (bid & 7) * cpx + (bid >> 3);
    const int bx = bid % nbx, by = bid / nbx;
    const int m0 = by << 8, n0 = bx << 8;

    const int srow = tid >> 3;
    const int scs  = ((tid & 7) ^ (srow & 7)) << 3;
    const unsigned short* gA = A  + (size_t)(m0 + srow) * K + scs;
    const unsigned short* gB = Bt + (size_t)(n0 + srow) * K + scs;
    const int frsw = fr & 7;

    f32x4_t acc[8][4];
    #pragma unroll
    for (int m = 0; m < 8; m++)
        #pragma unroll
        for (int n = 0; n < 4; n++)
            acc[m][n] = (f32x4_t){0.f, 0.f, 0.f, 0.f};

#define SA(T, q) gload_lds16(gA + (size_t)((q)*64)*K + (size_t)(T)*64, \
                             &smem[((T)&1)*G2_BUF + (q)*4096 + tid*8])
#define SB(T, q) gload_lds16(gB + (size_t)((q)*64)*K + (size_t)(T)*64, \
                             &smem[((T)&1)*G2_BUF + 16384 + (q)*4096 + tid*8])
#define RDA(T, MH, KI) { _Pragma("unroll") for (int mm = 0; mm < 4; ++mm) { \
    const int ro = ((T)&1)*G2_BUF + (wm*128 + (MH)*64 + mm*16 + fr)*64; \
    aF[mm] = *(const bf16x8_t*)&smem[ro + ((((KI)*4 + fq) ^ frsw) << 3)]; } }
#define RDB(T, KI, dst) { _Pragma("unroll") for (int nn = 0; nn < 4; ++nn) { \
    const int ro = ((T)&1)*G2_BUF + 16384 + (wn*64 + nn*16 + fr)*64; \
    dst[nn] = *(const bf16x8_t*)&smem[ro + ((((KI)*4 + fq) ^ frsw) << 3)]; } }
#define MM16(MH, BS) { __builtin_amdgcn_s_setprio(1); \
    _Pragma("unroll") for (int mm = 0; mm < 4; ++mm) \
    _Pragma("unroll") for (int nn = 0; nn < 4; ++nn) \
        acc[(MH)*4 + mm][nn] = __builtin_amdgcn_mfma_f32_16x16x32_bf16( \
            aF[mm], BS[nn], acc[(MH)*4 + mm][nn], 0, 0, 0); \
    __builtin_amdgcn_s_setprio(0); }

    SA(0,0); SA(0,1); SA(0,2); SA(0,3);
    SB(0,0); SB(0,1); SB(0,2); SB(0,3);
    SA(1,0); SA(1,2); SB(1,0); SB(1,1);
    vmcnt_wait<4>();
    BARF();

    for (int i = 0; i < NITER; ++i) {
        const int t0 = 2*i, t1 = 2*i + 1;
        bf16x8_t aF[4], b0[4], b1[4];

        RDA(t0, 0, 0); RDB(t0, 0, b0);
        SA(t1, 1); SA(t1, 3);
        BARF(); LGKMW(); MM16(0, b0); BARF();

        RDA(t0, 0, 1); RDB(t0, 1, b1);
        SB(t1, 2); SB(t1, 3);
        BARF(); LGKMW(); MM16(0, b1); BARF();

        RDA(t0, 1, 0);
        if (t0 + 2 < NT) { SA(t0 + 2, 0); SA(t0 + 2, 2); }
        BARF(); LGKMW(); MM16(1, b0); BARF();

        RDA(t0, 1, 1);
        if (t0 + 2 < NT) { SB(t0 + 2, 0); SB(t0 + 2, 1); }
        BARF(); LGKMW(); MM16(1, b1);
        if (i + 1 < NITER) { vmcnt_wait<4>(); } else { vmcnt_wait<0>(); }
        BARF();

        RDA(t1, 0, 0); RDB(t1, 0, b0);
        if (t0 + 2 < NT) { SA(t0 + 2, 1); SA(t0 + 2, 3); }
        BARF(); LGKMW(); MM16(0, b0); BARF();

        RDA(t1, 0, 1); RDB(t1, 1, b1);
        if (t0 + 2 < NT) { SB(t0 + 2, 2); SB(t0 + 2, 3); }
        BARF(); LGKMW(); MM16(0, b1); BARF();

        RDA(t1, 1, 0);
        if (t1 + 2 < NT) { SA(t1 + 2, 0); SA(t1 + 2, 2); }
        BARF(); LGKMW(); MM16(1, b0); BARF();

        RDA(t1, 1, 1);
        if (t1 + 2 < NT) { SB(t1 + 2, 0); SB(t1 + 2, 1); }
        BARF(); LGKMW(); MM16(1, b1);
        if (i + 1 < NITER) { vmcnt_wait<4>(); }
        BARF();
    }
#undef SA
#undef SB
#undef RDA
#undef RDB
#undef MM16

    // ---- coalesced epilogue: LDS-transpose to 1KB-contiguous float4 stores
    // Value mapping (m89 C/D layout): lane holds C[row_half][col] with
    //   row_half = m*16 + fq*4 + rr (0..127 within half wm), col = wn*64 +
    //   n*16 + fr (0..255). LDS = 128x256 fp32 (exactly 128KB).
    float* lf = (float*)smem;
    for (int h = 0; h < 2; ++h) {
        BARF();   // h=0: after K-loop; h=1: pass-0 reads done before overwrite
        if (wm == h) {
            #pragma unroll
            for (int m = 0; m < 8; m++)
                #pragma unroll
                for (int n = 0; n < 4; n++)
                    #pragma unroll
                    for (int rr = 0; rr < 4; rr++) {
                        const int row = m*16 + fq*4 + rr;
                        const int col = wn*64 + n*16 + fr;
                        lf[row*256 + (col ^ ((row & 7) << 2))] = acc[m][n][rr];
                    }
        }
        BARF();
        #pragma unroll
        for (int i = 0; i < 16; i++) {
            const int row = wave*16 + i;
            const int sw  = (row & 7) << 2;
            const float4 v = *(const float4*)&lf[row*256 + ((lane*4) ^ sw)];
            *(float4*)&C[(size_t)(m0 + h*128 + row) * N + n0 + lane*4] = v;
        }
    }
}

// --------- fused RMSNorm + RoPE + 16-token block-diagonal attention --------
__global__ __launch_bounds__(64) void attn_fused(const unsigned short* __restrict__ qkv,
                                                 const float* __restrict__ cosb,
                                                 const float* __restrict__ sinb,
                                                 const float* __restrict__ qw,
                                                 const float* __restrict__ kw,
                                                 unsigned short* __restrict__ out) {
    const int h    = blockIdx.x & (NH - 1);
    const int blk  = (blockIdx.x >> 4) & 127;
    const int b    = blockIdx.x >> 11;
    const int pos0 = blk * 16;
    const int kvh  = h >> 2;

    const int lane = threadIdx.x;
    const int r    = lane >> 2;
    const int qp   = lane & 3;
    const int d0   = qp * 16;

    __shared__ float qs[16][65];
    __shared__ float ks[16][65];
    __shared__ float vs[16][65];
    __shared__ float ps[16][17];

    const size_t rowb = ((size_t)(b * L_SEQ + pos0 + r)) * NQKV;
    const unsigned short* qptr = qkv + (rowb + h) * HD + d0;
    const unsigned short* kptr = qkv + (rowb + NH + kvh) * HD + d0;
    const unsigned short* vptr = qkv + (rowb + NH + NKV + kvh) * HD + d0;
    const size_t csrow = ((size_t)(b * L_SEQ + pos0 + r)) * HD + d0;

    float q[16], k[16], v[16], cs[16], sn[16];
    {
        ushort8_t q0 = *(const ushort8_t*)&qptr[0], q1 = *(const ushort8_t*)&qptr[8];
        ushort8_t k0 = *(const ushort8_t*)&kptr[0], k1 = *(const ushort8_t*)&kptr[8];
        ushort8_t v0 = *(const ushort8_t*)&vptr[0], v1 = *(const ushort8_t*)&vptr[8];
        #pragma unroll
        for (int i = 0; i < 8; i++) {
            q[i] = b2f(q0[i]); q[i+8] = b2f(q1[i]);
            k[i] = b2f(k0[i]); k[i+8] = b2f(k1[i]);
            v[i] = b2f(v0[i]); v[i+8] = b2f(v1[i]);
        }
        #pragma unroll
        for (int i = 0; i < 16; i += 4) {
            *(float4*)&cs[i] = *(const float4*)&cosb[csrow + i];
            *(float4*)&sn[i] = *(const float4*)&sinb[csrow + i];
        }
    }

    float sq = 0.f, sk = 0.f;
    #pragma unroll
    for (int i = 0; i < 16; i++) { sq += q[i]*q[i]; sk += k[i]*k[i]; }
    sq += __shfl_xor(sq, 1); sq += __shfl_xor(sq, 2);
    sk += __shfl_xor(sk, 1); sk += __shfl_xor(sk, 2);
    const float rq = rsqrtf(sq * (1.f / HD) + EPSV);
    const float rk = rsqrtf(sk * (1.f / HD) + EPSV);

    const float sgn = (qp < 2) ? -1.f : 1.f;
    #pragma unroll
    for (int i = 0; i < 16; i++) {
        float qn = q[i] * rq * qw[d0 + i];
        float kn = k[i] * rk * kw[d0 + i];
        float qo = __shfl_xor(qn, 2);
        float ko = __shfl_xor(kn, 2);
        qs[r][d0 + i] = qn * cs[i] + sgn * qo * sn[i];
        ks[r][d0 + i] = kn * cs[i] + sgn * ko * sn[i];
        vs[r][d0 + i] = v[i];
    }
    __syncthreads();

    float sc[4] = {0.f, 0.f, 0.f, 0.f};
    for (int d = 0; d < 64; d++) {
        const float qd = qs[r][d];
        sc[0] += qd * ks[qp     ][d];
        sc[1] += qd * ks[qp +  4][d];
        sc[2] += qd * ks[qp +  8][d];
        sc[3] += qd * ks[qp + 12][d];
    }
    #pragma unroll
    for (int cc = 0; cc < 4; cc++) {
        const int c = qp + cc * 4;
        sc[cc] = (c <= r) ? sc[cc] * 0.125f : -3.0e38f;
    }
    float mx = fmaxf(fmaxf(sc[0], sc[1]), fmaxf(sc[2], sc[3]));
    mx = fmaxf(mx, __shfl_xor(mx, 1));
    mx = fmaxf(mx, __shfl_xor(mx, 2));
    float e[4], sum = 0.f;
    #pragma unroll
    for (int cc = 0; cc < 4; cc++) { e[cc] = __expf(sc[cc] - mx); sum += e[cc]; }
    sum += __shfl_xor(sum, 1); sum += __shfl_xor(sum, 2);
    const float inv = 1.f / sum;
    #pragma unroll
    for (int cc = 0; cc < 4; cc++) ps[r][qp + cc * 4] = e[cc] * inv;
    __syncthreads();

    float o[16];
    #pragma unroll
    for (int i = 0; i < 16; i++) o[i] = 0.f;
    #pragma unroll
    for (int c = 0; c < 16; c++) {
        const float p = ps[r][c];
        #pragma unroll
        for (int i = 0; i < 16; i++) o[i] += p * vs[c][d0 + i];
    }

    __attribute__((aligned(16))) unsigned short ob[16];
    #pragma unroll
    for (int i = 0; i < 16; i++) ob[i] = f2b(o[i]);
    unsigned short* optr = out + (((size_t)(b * L_SEQ + pos0 + r) * NH + h) * HD) + d0;
    *(uint4*)optr       = *(uint4*)&ob[0];
    *((uint4*)optr + 1) = *(uint4*)&ob[8];
}

// ---------------------------------------------------------------------------
extern "C" void kernel_launch(void* const* d_in, const int* in_sizes, int n_in,
                              void* d_out, int out_size, void* d_ws, size_t ws_size,
                              hipStream_t stream) {
    const float* hid  = (const float*)d_in[0];
    const float* cosb = (const float*)d_in[2];
    const float* sinb = (const float*)d_in[3];
    const float* Wqkv = (const float*)d_in[4];
    const float* Wo   = (const float*)d_in[5];
    const float* qw   = (const float*)d_in[6];
    const float* kw   = (const float*)d_in[7];
    float* outp = (float*)d_out;

    char* ws = (char*)d_ws;
    unsigned short* Hb    = (unsigned short*)ws; ws += (size_t)M_ROWS * HID * 2;
    unsigned short* WqkvT = (unsigned short*)ws; ws += (size_t)QKV_N * HID * 2;
    unsigned short* WoT   = (unsigned short*)ws; ws += (size_t)HID * O_N * 2;
    unsigned short* qkvb  = (unsigned short*)ws; ws += (size_t)M_ROWS * QKV_N * 2;
    unsigned short* attnb = (unsigned short*)ws;

    // prep: cvt + both transposes in ONE launch
    prep<<<dim3(CVT_BLKS + 6144 + 4096), 256, 0, stream>>>
        (hid, Hb, Wqkv, WqkvT, Wo, WoT);

    // GEMM1 (measured best): 128x192, BK=64, NBUF=3, 256 blocks
    gemm_sb<128, 192, 64, 3, 2, 4, true, unsigned short>
        <<<dim3((M_ROWS / 128) * (QKV_N / 192)), 512, 0, stream>>>
        (Hb, WqkvT, qkvb, M_ROWS, QKV_N, HID);

    // fused rmsnorm + rope + block-diag attention (bf16 in/out)
    attn_fused<<<dim3(B_SZ * (L_SEQ / 16) * NH), 64, 0, stream>>>(qkvb, cosb, sinb, qw, kw, attnb);

    // GEMM2: 8-phase 256^2 + coalesced LDS-transpose epilogue
    gemm2_8p<<<dim3((M_ROWS / 256) * (HID / 256)), 512, 0, stream>>>
        (attnb, WoT, outp);
}